// Round 12
// baseline (80.935 us; speedup 1.0000x reference)
//
#include <hip/hip_runtime.h>
#include <hip/hip_bf16.h>

#define NB 4096
#define ND 512

typedef int i32x4 __attribute__((ext_vector_type(4)));
typedef int i32x8 __attribute__((ext_vector_type(8)));
typedef float f32x4 __attribute__((ext_vector_type(4)));

#define AS1 __attribute__((address_space(1)))
#define AS3 __attribute__((address_space(3)))

// ---- f32 -> fp8 e4m3fn (OCP), RNE, |x| <= 1 ----
__device__ __forceinline__ unsigned int f2e4m3(float x) {
    float a = fabsf(x);
    unsigned s = (__float_as_uint(x) >> 24) & 0x80u;
    if (a < 0.015625f) {
        int q = __float2int_rn(a * 512.0f);
        return s | (unsigned)q;
    }
    unsigned u = __float_as_uint(a);
    u += 0x7FFFFu + ((u >> 20) & 1u);
    unsigned e8 = (u >> 23) - 120u;
    unsigned m = (u >> 20) & 7u;
    return s | (e8 << 3) | m;
}

// ---------------- normalize + cast to fp8 (wave per row) + zero-init sums ----------------
__global__ __launch_bounds__(256) void nrm_kernel(
    const float* __restrict__ z0, const float* __restrict__ z1,
    const float* __restrict__ z2, unsigned char* __restrict__ nrm8,
    float* __restrict__ rowsum, float* __restrict__ colsum)
{
    const int w = threadIdx.x >> 6, lane = threadIdx.x & 63;
    const int row = blockIdx.x * 4 + w;
    const int p = blockIdx.y;
    if (lane == 0) {
        rowsum[p * NB + row] = 0.f;
        colsum[p * NB + row] = 0.f;
    }
    const float* z = (p == 0) ? z0 : (p == 1) ? z1 : z2;
    const float4* zr = (const float4*)(z + (size_t)row * ND);
    const float4 a = zr[lane * 2], b = zr[lane * 2 + 1];
    float ss = a.x * a.x + a.y * a.y + a.z * a.z + a.w * a.w
             + b.x * b.x + b.y * b.y + b.z * b.z + b.w * b.w;
    #pragma unroll
    for (int m = 32; m >= 1; m >>= 1) ss += __shfl_xor(ss, m);
    const float inv = 1.0f / fmaxf(sqrtf(ss), 1e-8f);
    uint2 o;
    o.x = f2e4m3(a.x * inv) | (f2e4m3(a.y * inv) << 8)
        | (f2e4m3(a.z * inv) << 16) | (f2e4m3(a.w * inv) << 24);
    o.y = f2e4m3(b.x * inv) | (f2e4m3(b.y * inv) << 8)
        | (f2e4m3(b.z * inv) << 16) | (f2e4m3(b.w * inv) << 24);
    *(uint2*)(nrm8 + ((size_t)p * NB + row) * ND + lane * 8) = o;
}

// ---------------- fused pair GEMM, MX-fp8: 128 rows x 512 cols per block ----------------
// 32 stages (8 bx-subtiles x 4 k). A x3 (16 KB) + B x3 (8 KB) = 72 KB -> 2
// blocks/CU. TRUE 2-deep pipeline: stage s issues STAGE(s+2) first, then
// vmcnt(6) drains only s+1 (s+2 stays in flight across 2 stages), barrier,
// LDF(s+1) interleaved with MFMA(s). Wave tile 64x32 (acc 4x2).
__global__ __launch_bounds__(256, 2) void pair_gemm_kernel(
    const unsigned char* __restrict__ nrm8,
    float* __restrict__ rowsum, float* __restrict__ colsum,
    float* __restrict__ diag)
{
    // 768 blocks: bxc = bid&7 (512-col B chunk per XCD, 768 KB L2-resident);
    // r = bid>>3: p = r>>5, by = r&31.
    const int bid = blockIdx.x;
    const int bxc = bid & 7;
    const int r = bid >> 3;
    const int p = r >> 5;
    const int by = r & 31;
    const int ia = (p == 2) ? 1 : 0;
    const int ib = (p == 0) ? 1 : 2;

    const char* Ag = (const char*)nrm8 + ((size_t)ia * NB + (size_t)by * 128) * ND;
    const char* Bg = (const char*)nrm8 + ((size_t)ib * NB + (size_t)bxc * 512) * ND;

    __shared__ char lds[73728];  // A: 3 x 16KB at 0; B: 3 x 8KB at 49152

    const int tid = threadIdx.x;
    const int lane = tid & 63;
    const int w = tid >> 6;
    const int wr = w >> 1, wc = w & 1;   // 2x2 waves; wave tile 64(M) x 32(N)
    const int lr = lane & 15, lg = lane >> 4;

    // staging maps (proven r6-r11): chunk c -> LDS linear c*16; source row
    // rr = c>>3, phys slot qp = c&7 holds logical qp^(rr&7) (rule 21).
    int srcOffA[4], srcOffB[2];
    #pragma unroll
    for (int q = 0; q < 4; ++q) {
        const int c = q * 256 + tid;
        const int rr = c >> 3;
        srcOffA[q] = rr * ND + (((c & 7) ^ (rr & 7)) * 16);
    }
    #pragma unroll
    for (int q = 0; q < 2; ++q) {
        const int c = q * 256 + tid;
        const int rr = c >> 3;
        srcOffB[q] = rr * ND + (((c & 7) ^ (rr & 7)) * 16);
    }

    // frag reads: logical slots {2lg, 2lg+1}, phys = ^(lr&7) (proven).
    const int s0 = ((2 * lg) ^ (lr & 7)) * 16;
    const int s1 = ((2 * lg + 1) ^ (lr & 7)) * 16;
    int arow[4], brow[2];
    #pragma unroll
    for (int m = 0; m < 4; ++m) arow[m] = (wr * 64 + m * 16 + lr) * 128;
    #pragma unroll
    for (int n = 0; n < 2; ++n) brow[n] = (wc * 32 + n * 16 + lr) * 128;

    f32x4 acc[4][2] = {};
    float rs[4][4];
    #pragma unroll
    for (int m = 0; m < 4; ++m)
        #pragma unroll
        for (int j = 0; j < 4; ++j) rs[m][j] = 0.f;

    #define STAGE_A(ksl, dstbase) do {                                              \
        _Pragma("unroll")                                                           \
        for (int q = 0; q < 4; ++q)                                                 \
            __builtin_amdgcn_global_load_lds(                                       \
                (const AS1 void*)(Ag + srcOffA[q] + (ksl) * 128),                   \
                (AS3 void*)(lds + (dstbase) + q * 4096 + tid * 16), 16, 0, 0);      \
    } while (0)
    #define STAGE_B(bxl, ksl, dstbase) do {                                         \
        _Pragma("unroll")                                                           \
        for (int q = 0; q < 2; ++q)                                                 \
            __builtin_amdgcn_global_load_lds(                                       \
                (const AS1 void*)(Bg + (bxl) * 32768 + srcOffB[q] + (ksl) * 128),   \
                (AS3 void*)(lds + 49152 + (dstbase) + q * 4096 + tid * 16), 16, 0, 0); \
    } while (0)

    #define LDF(dst, base) do {                                                     \
        i32x4 lo_ = *(const i32x4*)((base) + s0);                                   \
        i32x4 hi_ = *(const i32x4*)((base) + s1);                                   \
        dst = __builtin_shufflevector(lo_, hi_, 0, 1, 2, 3, 4, 5, 6, 7);            \
    } while (0)

    #define LDFRAGS(afX, bfX, idx) do {                                             \
        const char* aB_ = lds + (idx) * 16384;                                      \
        const char* bB_ = lds + 49152 + (idx) * 8192;                               \
        _Pragma("unroll")                                                           \
        for (int m = 0; m < 4; ++m) LDF(afX[m], aB_ + arow[m]);                     \
        _Pragma("unroll")                                                           \
        for (int n = 0; n < 2; ++n) LDF(bfX[n], bB_ + brow[n]);                     \
    } while (0)

    #define SC 0x7F7F7F7F
    #define MFMA8(afX, bfX) do {                                                    \
        __builtin_amdgcn_s_setprio(1);                                              \
        _Pragma("unroll")                                                           \
        for (int m = 0; m < 4; ++m)                                                 \
            _Pragma("unroll")                                                       \
            for (int n = 0; n < 2; ++n)                                             \
                acc[m][n] = __builtin_amdgcn_mfma_scale_f32_16x16x128_f8f6f4(       \
                    afX[m], bfX[n], acc[m][n], 0, 0, 0, SC, 0, SC);                 \
        __builtin_amdgcn_s_setprio(0);                                              \
    } while (0)

    constexpr float C10 = 14.42695040888963f;

    // epilogue for bx-subtile bxl (after k=3): exp, colsum atomics, diag, reset
    #define EPILOGUE(bxl) do {                                                      \
        const int bxg_ = bxc * 8 + (bxl);                                           \
        float cs_[2] = {0.f, 0.f};                                                  \
        _Pragma("unroll")                                                           \
        for (int m = 0; m < 4; ++m)                                                 \
            _Pragma("unroll")                                                       \
            for (int n = 0; n < 2; ++n)                                             \
                _Pragma("unroll")                                                   \
                for (int j = 0; j < 4; ++j) {                                       \
                    float e = exp2f(fmaf(acc[m][n][j], C10, -C10));                 \
                    rs[m][j] += e;                                                  \
                    cs_[n] += e;                                                    \
                }                                                                   \
        if (bxg_ == by * 2 + wr) {                                                  \
            _Pragma("unroll")                                                       \
            for (int m = 0; m < 4; ++m) {                                           \
                if (wc == (m >> 1) && lg == (lr >> 2)) {                            \
                    f32x4 dv = acc[m][m & 1];                                       \
                    const int jj = lr & 3;                                          \
                    float val = (jj == 0) ? dv[0] : (jj == 1) ? dv[1]               \
                              : (jj == 2) ? dv[2] : dv[3];                          \
                    diag[p * NB + by * 128 + wr * 64 + m * 16 + lr] = val;          \
                }                                                                   \
            }                                                                       \
        }                                                                           \
        _Pragma("unroll")                                                           \
        for (int n = 0; n < 2; ++n) {                                               \
            float v = cs_[n];                                                       \
            v += __shfl_xor(v, 16);                                                 \
            v += __shfl_xor(v, 32);                                                 \
            if (lg == 0)                                                            \
                atomicAdd(&colsum[p * NB + bxg_ * 64 + wc * 32 + n * 16 + lr], v);  \
        }                                                                           \
        _Pragma("unroll")                                                           \
        for (int m = 0; m < 4; ++m)                                                 \
            _Pragma("unroll")                                                       \
            for (int n = 0; n < 2; ++n)                                             \
                acc[m][n] = (f32x4){0.f, 0.f, 0.f, 0.f};                            \
    } while (0)

    // prologue: stage 0 -> idx0, stage 1 -> idx1; drain stage 0 only
    STAGE_A(0, 0);           STAGE_B(0, 0, 0);
    STAGE_A(1, 16384);       STAGE_B(0, 1, 8192);
    asm volatile("s_waitcnt vmcnt(6)" ::: "memory");
    __builtin_amdgcn_s_barrier();

    i32x8 afA[4], bfA[2], afB[4], bfB[2];
    LDFRAGS(afA, bfA, 0);    // frags(0)

    int idxL = 1;  // buffer of stage s+1 (LDF target)
    int idxS = 2;  // buffer of stage s+2 (STAGE target)

    #pragma unroll 1
    for (int tt = 0; tt < 16; ++tt) {
        // ---------- even stage s = 2tt: MFMA uses fA, LDF fills fB ----------
        {
            const int s2 = 2 * tt + 2;     // stage being issued
            if (tt < 15) {
                STAGE_A(s2 & 3, idxS * 16384);
                STAGE_B(s2 >> 2, s2 & 3, idxS * 8192);
            }
            if (tt == 15)           asm volatile("s_waitcnt vmcnt(0) lgkmcnt(0)" ::: "memory");
            else if (tt > 0 && (tt & 1) == 0)
                                    asm volatile("s_waitcnt vmcnt(8) lgkmcnt(0)" ::: "memory");
            else                    asm volatile("s_waitcnt vmcnt(6) lgkmcnt(0)" ::: "memory");
            __builtin_amdgcn_s_barrier();
            LDFRAGS(afB, bfB, idxL);       // frags(2tt+1)
            MFMA8(afA, bfA);               // stage 2tt
            idxL = (idxL == 2) ? 0 : idxL + 1;
            idxS = (idxS == 2) ? 0 : idxS + 1;
        }
        // ---------- odd stage s = 2tt+1: MFMA uses fB, LDF fills fA ----------
        {
            const int s2 = 2 * tt + 3;
            if (tt < 15) {
                STAGE_A(s2 & 3, idxS * 16384);
                STAGE_B(s2 >> 2, s2 & 3, idxS * 8192);
                asm volatile("s_waitcnt vmcnt(6) lgkmcnt(0)" ::: "memory");
                __builtin_amdgcn_s_barrier();
                LDFRAGS(afA, bfA, idxL);   // frags(2tt+2)
            }
            MFMA8(afB, bfB);               // stage 2tt+1
            if (tt & 1) EPILOGUE(tt >> 1); // (s&3)==3
            idxL = (idxL == 2) ? 0 : idxL + 1;
            idxS = (idxS == 2) ? 0 : idxS + 1;
        }
    }
    #undef STAGE_A
    #undef STAGE_B
    #undef LDF
    #undef LDFRAGS
    #undef MFMA8
    #undef EPILOGUE

    // ---- final rowsum flush (accumulated over all 8 bx-subtiles) ----
    #pragma unroll
    for (int m = 0; m < 4; ++m)
        #pragma unroll
        for (int j = 0; j < 4; ++j) {
            float v = rs[m][j];
            v += __shfl_xor(v, 1);
            v += __shfl_xor(v, 2);
            v += __shfl_xor(v, 4);
            v += __shfl_xor(v, 8);
            if (lr == 0)
                atomicAdd(&rowsum[p * NB + by * 128 + wr * 64 + m * 16 + lg * 4 + j], v);
        }
}

// ---------------- final reduce: 48 blocks, atomic accumulate ----------------
__global__ __launch_bounds__(256) void finalize_kernel(
    const float* __restrict__ rowsum, const float* __restrict__ colsum,
    const float* __restrict__ diag, float* __restrict__ out)
{
    const int i = blockIdx.x * 256 + threadIdx.x;   // 48*256 = 12288 exactly
    float s = 0.5f * (logf(rowsum[i]) + logf(colsum[i])) + 10.0f - 10.0f * diag[i];
    #pragma unroll
    for (int m = 32; m >= 1; m >>= 1) s += __shfl_xor(s, m);
    __shared__ float sw[4];
    if ((threadIdx.x & 63) == 0) sw[threadIdx.x >> 6] = s;
    __syncthreads();
    if (threadIdx.x == 0)
        atomicAdd(out, (sw[0] + sw[1] + sw[2] + sw[3]) * (1.0f / (3.0f * NB)));
}

extern "C" void kernel_launch(void* const* d_in, const int* in_sizes, int n_in,
                              void* d_out, int out_size, void* d_ws, size_t ws_size,
                              hipStream_t stream) {
    const float* z0 = (const float*)d_in[0];
    const float* z1 = (const float*)d_in[1];
    const float* z2 = (const float*)d_in[2];
    float* out = (float*)d_out;

    char* ws = (char*)d_ws;
    unsigned char* nrm8 = (unsigned char*)ws;               // 3*4096*512 fp8 = 6.3 MB
    const size_t nrm_bytes = (size_t)3 * NB * ND;
    float* rowsum = (float*)(ws + nrm_bytes);               // 3*4096 f32
    float* colsum = rowsum + 3 * NB;                        // 3*4096 f32
    float* diag = colsum + 3 * NB;                          // 3*4096 f32 (fully overwritten)

    hipMemsetAsync(out, 0, sizeof(float), stream);
    nrm_kernel<<<dim3(NB / 4, 3), 256, 0, stream>>>(z0, z1, z2, nrm8, rowsum, colsum);
    pair_gemm_kernel<<<768, 256, 0, stream>>>(nrm8, rowsum, colsum, diag);
    finalize_kernel<<<48, 256, 0, stream>>>(rowsum, colsum, diag, out);
}